// Round 2
// baseline (306.962 us; speedup 1.0000x reference)
//
#include <hip/hip_runtime.h>

// QuantizedBottleneck via i8 MFMA implicit GEMM. Exact integer math.
//   prep  : pack MFMA A-fragments (w1/w2/w3 -> i8) + wsum1 into d_ws
//   conv1 : 1x1 256->64 + bn1 -> t1 [n][64] i8 (64-px tiles, perm-pack, reg dbuf)
//   conv23: fused 3x3 64->64 pad1 + bn2 -> LDS, then 1x1 64->256 + bn3 +
//           residual add -> out int32. 1-row tiles (64 px padded), grid (56,32).
// Requant uses the exact single-shift identity:
//   ((p+nudge)>>31 + 2^(sh-1))>>sh == (p + nudge + 2^(30+sh)) >> (31+sh)
// with nudge selected on sign of p; shift>=32 done as hi-dword >> (sh-1).
// conv1 packs raw x bytes ^0x80 (= x-128) and corrects acc by (128-zin)*wsum.
// MFMA 16x16x64_i8: A[m=lane&15][k=(lane>>4)*16+j], B[k][n=lane&15],
// C/D: col=lane&15, row=(lane>>4)*4+reg.

typedef int v4i __attribute__((ext_vector_type(4)));

#define BATCH 32
#define CIN 256
#define CMID 64
#define HW 3136
#define W56 56

#define WP_BYTES ((size_t)68 * 64 * 16)
#define WSUM_BYTES ((size_t)64 * 4)

__device__ __forceinline__ int rq_apply(int acc, int m0, long long cp, long long cn,
                                        int shm1, int zo) {
    long long prod = (long long)acc * m0;
    prod += (prod >= 0) ? cp : cn;
    int hi = (int)((unsigned long long)prod >> 32);
    int v = (hi >> shm1) + zo;
    return v < 0 ? 0 : (v > 255 ? 255 : v);
}

__device__ __forceinline__ int ms_apply(int xin, int m0, long long cp, long long cn,
                                        int shm1) {
    long long prod = (long long)xin * m0;
    prod += (prod >= 0) ? cp : cn;
    return ((int)((unsigned long long)prod >> 32)) >> shm1;
}

// gather byte0 of four ints -> one dword (3 x v_perm_b32)
__device__ __forceinline__ unsigned int pk4x(int a0, int a1, int a2, int a3) {
    unsigned p01 = __builtin_amdgcn_perm((unsigned)a1, (unsigned)a0, 0x00000400u);
    unsigned p23 = __builtin_amdgcn_perm((unsigned)a3, (unsigned)a2, 0x04000000u);
    return __builtin_amdgcn_perm(p23, p01, 0x07060100u);
}

__device__ __forceinline__ v4i pack16f(const float* src, int stride) {
    v4i r;
#pragma unroll
    for (int d = 0; d < 4; ++d) {
        unsigned int u = 0;
#pragma unroll
        for (int by = 0; by < 4; ++by) {
            int v = (int)src[(d * 4 + by) * stride];
            u |= ((unsigned int)(v & 255)) << (8 * by);
        }
        r[d] = (int)u;
    }
    return r;
}

// -------- prep: fragsets w1 [0,16), w2 [16,52), w3 [52,68); block 17: wsum1 --
__global__ __launch_bounds__(256) void k_prep(
    const float* __restrict__ w1, const float* __restrict__ w2,
    const float* __restrict__ w3, v4i* __restrict__ wp, int* __restrict__ wsum)
{
    if (blockIdx.x < 17) {
        int id = blockIdx.x * 256 + threadIdx.x;
        int fid = id >> 6, lane = id & 63;
        int col = lane & 15, ci0 = (lane >> 4) * 16;
        const float* src;
        int stride;
        if (fid < 16) {
            int wv = fid >> 2, ks = fid & 3;
            src = w1 + (size_t)(wv * 16 + col) * 256 + ks * 64 + ci0;
            stride = 1;
        } else if (fid < 52) {
            int i = fid - 16, wv = i / 9, t = i - wv * 9;
            src = w2 + ((size_t)(wv * 16 + col) * 64 + ci0) * 9 + t;
            stride = 9;
        } else {
            int s = fid - 52;
            src = w3 + (size_t)(s * 16 + col) * 64 + ci0;
            stride = 1;
        }
        wp[fid * 64 + lane] = pack16f(src, stride);
    } else {
        // wsum1[co] = sum_ci w1[co][ci]  (4 threads per channel)
        int ch = threadIdx.x >> 2, t4 = threadIdx.x & 3;
        int s = 0;
        for (int i = 0; i < 64; ++i) s += (int)w1[(size_t)ch * 256 + t4 * 64 + i];
        s += __shfl_xor(s, 1);
        s += __shfl_xor(s, 2);
        if (t4 == 0) wsum[ch] = s;
    }
}

// -------- conv1: 1x1 256->64 + bn1 -> t1. grid (49, 32), 64-px tiles --------
// Staging: thread (cg=tid&15, q=tid>>4) loads 4 int4 (4 px, 4 ci) per K-step,
// perm-packs to i8 (^0x80), b32 LDS writes (2-way, free). Register dbuf.
__global__ __launch_bounds__(256, 5) void k_conv1(
    const int* __restrict__ x, const v4i* __restrict__ wp1,
    const int* __restrict__ wsum1,
    const float* __restrict__ bn_w, const float* __restrict__ bn_b,
    const int* __restrict__ conv_zin, const int* __restrict__ conv_m0,
    const int* __restrict__ conv_shift, const int* __restrict__ conv_zout,
    const int* __restrict__ bn_m0, const int* __restrict__ bn_shift,
    const int* __restrict__ bn_zout, signed char* __restrict__ t1)
{
    __shared__ v4i sm[320];                        // 64 px x 80 B
    const int tid = threadIdx.x, lane = tid & 63, wv = tid >> 6;
    const int col = lane & 15, koff = lane >> 4;
    const int b = blockIdx.y;
    const int hw0 = blockIdx.x * 64;
    const int co0 = wv * 16;

    v4i a[4];
#pragma unroll
    for (int ks = 0; ks < 4; ++ks) a[ks] = wp1[(wv * 4 + ks) * 64 + lane];

    const int cg = tid & 15, q = tid >> 4;         // all 256 threads stage
    const int* xbase = x + (size_t)b * CIN * HW + hw0 + 4 * q;

    v4i xa[4], xa2[4];
#pragma unroll
    for (int j = 0; j < 4; ++j)
        xa[j] = *(const v4i*)(xbase + (size_t)(cg * 4 + j) * HW);

    v4i acc[4];
#pragma unroll
    for (int i = 0; i < 4; ++i) acc[i] = (v4i){0, 0, 0, 0};

    unsigned* smx = (unsigned*)sm;
#pragma unroll
    for (int ks = 0; ks < 4; ++ks) {
        if (ks) __syncthreads();                   // prior MFMA reads done
#pragma unroll
        for (int p = 0; p < 4; ++p) {
            unsigned pkd = pk4x(xa[0][p], xa[1][p], xa[2][p], xa[3][p]) ^ 0x80808080u;
            smx[(q * 4 + p) * 20 + cg] = pkd;
        }
        __syncthreads();
        if (ks < 3) {                              // prefetch next K-step
#pragma unroll
            for (int j = 0; j < 4; ++j)
                xa2[j] = *(const v4i*)(xbase + (size_t)((ks + 1) * 64 + cg * 4 + j) * HW);
        }
#pragma unroll
        for (int nt = 0; nt < 4; ++nt) {
            v4i bf = sm[(nt * 16 + col) * 5 + koff];
            acc[nt] = __builtin_amdgcn_mfma_i32_16x16x64_i8(a[ks], bf, acc[nt], 0, 0, 0);
        }
        if (ks < 3) {
#pragma unroll
            for (int j = 0; j < 4; ++j) xa[j] = xa2[j];
        }
    }

    const int zin = conv_zin[0];
    const int corr0 = 128 - zin;                   // acc was computed vs x-128
    const int cm0 = conv_m0[0], csh = conv_shift[0], czo = conv_zout[0];
    const int bm0 = bn_m0[0], bsh = bn_shift[0], bzo = bn_zout[0];
    const int zin2 = conv_zin[1];
    const long long cbv = 1LL << (30 + csh);
    const long long ccp = cbv + (1LL << 30), ccn = cbv + 1 - (1LL << 30);
    const int cshm1 = csh - 1;
    const long long bbv = 1LL << (30 + bsh);
    const long long bcp = bbv + (1LL << 30), bcn = bbv + 1 - (1LL << 30);
    const int bshm1 = bsh - 1;
    const int rowb = koff * 4;
    int bw[4], bbx[4], ws[4];
#pragma unroll
    for (int r = 0; r < 4; ++r) {
        bw[r] = (int)bn_w[co0 + rowb + r];
        bbx[r] = (int)bn_b[co0 + rowb + r] - czo * bw[r];
        ws[r] = wsum1[co0 + rowb + r];
    }
#pragma unroll
    for (int nt = 0; nt < 4; ++nt) {
        int n = b * HW + hw0 + nt * 16 + col;
        int e[4];
#pragma unroll
        for (int r = 0; r < 4; ++r) {
            int av = acc[nt][r] + corr0 * ws[r];
            int qv = rq_apply(av, cm0, ccp, ccn, cshm1, czo);
            int a2 = qv * bw[r] + bbx[r];
            int q2 = rq_apply(a2, bm0, bcp, bcn, bshm1, bzo);
            e[r] = q2 - zin2;
        }
        *(unsigned*)(t1 + (size_t)n * 64 + co0 + rowb) = pk4x(e[0], e[1], e[2], e[3]);
    }
}

// -------- conv23: fused 3x3+bn2 (-> LDS) then 1x1 64->256 + bn3 + residual --
// grid (56, 32): 1 output row (64 px, 56 valid) x batch.
// Phase A: conv2 over 3 halo rows in sm -> t2s LDS (B-frag layout).
// Phase B: 4 fragset steps, software-pipelined residual x loads.
__global__ __launch_bounds__(256, 5) void k_conv23(
    const signed char* __restrict__ t1, const v4i* __restrict__ wp2,
    const v4i* __restrict__ wp3,
    const float* __restrict__ bn2_w, const float* __restrict__ bn2_b,
    const float* __restrict__ bn3_w, const float* __restrict__ bn3_b,
    const int* __restrict__ x,
    const int* __restrict__ conv_zin, const int* __restrict__ conv_m0,
    const int* __restrict__ conv_shift, const int* __restrict__ conv_zout,
    const int* __restrict__ bn_m0, const int* __restrict__ bn_shift,
    const int* __restrict__ bn_zout,
    const int* __restrict__ add_z, const int* __restrict__ add_m0,
    const int* __restrict__ add_shift, const int* __restrict__ add_zout,
    int* __restrict__ out)
{
    __shared__ v4i sm[840];                       // 3 rows x 56 px x 80 B
    __shared__ v4i t2s[320];                      // 64 px x 80 B
    const int tid = threadIdx.x, lane = tid & 63, wv = tid >> 6;
    const int col = lane & 15, koff = lane >> 4;
    const int b = blockIdx.y;
    const int r0 = blockIdx.x;
    const int co0 = wv * 16, rowb = koff * 4;

    v4i a[9];
#pragma unroll
    for (int t = 0; t < 9; ++t) a[t] = wp2[(wv * 9 + t) * 64 + lane];

    const v4i* t1v = (const v4i*)t1;
#pragma unroll
    for (int k = 0; k < 3; ++k) {
        int idx = tid + k * 256;
        if (idx < 672) {                          // 168 px x 4 parts
            int pixl = idx >> 2, part = idx & 3;
            int lrow = pixl / W56, gw = pixl - lrow * W56;
            int grow = r0 - 1 + lrow;
            v4i v = (v4i){0, 0, 0, 0};
            if ((unsigned)grow < 56u)
                v = t1v[((size_t)b * HW + grow * W56 + gw) * 4 + part];
            sm[pixl * 5 + part] = v;
        }
    }
    __syncthreads();

    v4i acc[4];
#pragma unroll
    for (int i = 0; i < 4; ++i) acc[i] = (v4i){0, 0, 0, 0};

#pragma unroll
    for (int kh = 0; kh < 3; ++kh) {
#pragma unroll
        for (int kw = 0; kw < 3; ++kw) {
            v4i af = a[kh * 3 + kw];
#pragma unroll
            for (int nt = 0; nt < 4; ++nt) {
                int sw = nt * 16 + col + kw - 1;
                bool valid = (unsigned)sw < 56u;
                v4i bf = sm[(kh * W56 + (valid ? sw : 0)) * 5 + koff];
                if (!valid) { bf[0] = 0; bf[1] = 0; bf[2] = 0; bf[3] = 0; }
                acc[nt] = __builtin_amdgcn_mfma_i32_16x16x64_i8(af, bf, acc[nt], 0, 0, 0);
            }
        }
    }

    // hoist conv3 A-frags + step-0 residual x loads (independent of t2s);
    // their latency hides under phase-A epilogue + barrier.
    v4i a3x[4];
#pragma unroll
    for (int s = 0; s < 4; ++s) a3x[s] = wp3[(wv * 4 + s) * 64 + lane];

    int pxc[4];
#pragma unroll
    for (int nt = 0; nt < 4; ++nt) {
        int px = nt * 16 + col;
        pxc[nt] = px < 56 ? px : 55;
    }
    const size_t xoff = (size_t)b * CIN * HW + (size_t)rowb * HW + r0 * W56;
    const int* xb = x + xoff;
    int* ob = out + xoff;

    int xv[4][4];
#pragma unroll
    for (int nt = 0; nt < 4; ++nt)
#pragma unroll
        for (int r = 0; r < 4; ++r)
            xv[nt][r] = xb[(size_t)(wv * 64 + r) * HW + pxc[nt]];

    {   // phase A epilogue: requant + bn2, perm-pack -> t2s (B-frag layout)
        const int cm0 = conv_m0[1], csh = conv_shift[1], czo = conv_zout[1];
        const int bm0 = bn_m0[1], bsh = bn_shift[1], bzo = bn_zout[1];
        const int zin3 = conv_zin[2];
        const long long cbv = 1LL << (30 + csh);
        const long long ccp = cbv + (1LL << 30), ccn = cbv + 1 - (1LL << 30);
        const int cshm1 = csh - 1;
        const long long bbv = 1LL << (30 + bsh);
        const long long bcp = bbv + (1LL << 30), bcn = bbv + 1 - (1LL << 30);
        const int bshm1 = bsh - 1;
        int bw[4], bbx[4];
#pragma unroll
        for (int r = 0; r < 4; ++r) {
            bw[r] = (int)bn2_w[co0 + rowb + r];
            bbx[r] = (int)bn2_b[co0 + rowb + r] - czo * bw[r];
        }
#pragma unroll
        for (int nt = 0; nt < 4; ++nt) {
            int pix = nt * 16 + col;
            int e[4];
#pragma unroll
            for (int r = 0; r < 4; ++r) {
                int qv = rq_apply(acc[nt][r], cm0, ccp, ccn, cshm1, czo);
                int a2 = qv * bw[r] + bbx[r];
                int q2 = rq_apply(a2, bm0, bcp, bcn, bshm1, bzo);
                e[r] = q2 - zin3;
            }
            *(unsigned*)((char*)t2s + (size_t)(pix * 5 + wv) * 16 + koff * 4) =
                pk4x(e[0], e[1], e[2], e[3]);
        }
    }
    __syncthreads();

    // ---- phase B: 1x1 64->256 + bn3 + residual add ----
    const int cm0 = conv_m0[2], csh = conv_shift[2], czo = conv_zout[2];
    const int bm0 = bn_m0[2], bsh = bn_shift[2], bzo = bn_zout[2];
    const long long cb3 = 1LL << (30 + csh);
    const long long ccp = cb3 + (1LL << 30), ccn = cb3 + 1 - (1LL << 30);
    const int cshm1 = csh - 1;
    const long long bb3 = 1LL << (30 + bsh);
    const long long bcp = bb3 + (1LL << 30), bcn = bb3 + 1 - (1LL << 30);
    const int bshm1 = bsh - 1;
    const int az0 = add_z[0], az1 = add_z[1];
    const int am0 = add_m0[0], am1 = add_m0[1];
    const int ash0 = add_shift[0], ash1 = add_shift[1];
    const long long a0b = 1LL << (30 + ash0);
    const long long acp0 = a0b + (1LL << 30), acn0 = a0b + 1 - (1LL << 30);
    const int ashm0 = ash0 - 1;
    const long long a1b = 1LL << (30 + ash1);
    const long long acp1 = a1b + (1LL << 30), acn1 = a1b + 1 - (1LL << 30);
    const int ashm1 = ash1 - 1;
    const int azout = add_zout[0];

#pragma unroll
    for (int s = 0; s < 4; ++s) {
        const int c0 = wv * 64 + s * 16;
        int xn[4][4];
        if (s < 3) {                              // prefetch next step's residual
#pragma unroll
            for (int nt = 0; nt < 4; ++nt)
#pragma unroll
                for (int r = 0; r < 4; ++r)
                    xn[nt][r] = xb[(size_t)(c0 + 16 + r) * HW + pxc[nt]];
        }
        v4i acc3[4];
#pragma unroll
        for (int i = 0; i < 4; ++i) acc3[i] = (v4i){0, 0, 0, 0};
#pragma unroll
        for (int nt = 0; nt < 4; ++nt) {
            v4i bf = t2s[(nt * 16 + col) * 5 + koff];
            acc3[nt] = __builtin_amdgcn_mfma_i32_16x16x64_i8(a3x[s], bf, acc3[nt], 0, 0, 0);
        }
        int bw3[4], bbx3[4];
#pragma unroll
        for (int r = 0; r < 4; ++r) {
            bw3[r] = (int)bn3_w[c0 + rowb + r];
            bbx3[r] = (int)bn3_b[c0 + rowb + r] - czo * bw3[r];
        }
#pragma unroll
        for (int nt = 0; nt < 4; ++nt) {
            bool st = (nt * 16 + col) < 56;
#pragma unroll
            for (int r = 0; r < 4; ++r) {
                int qv = rq_apply(acc3[nt][r], cm0, ccp, ccn, cshm1, czo);
                int a2 = qv * bw3[r] + bbx3[r];
                int q2 = rq_apply(a2, bm0, bcp, bcn, bshm1, bzo);
                int ra = ms_apply(xv[nt][r] - az0, am0, acp0, acn0, ashm0);
                int rb = ms_apply(q2 - az1, am1, acp1, acn1, ashm1);
                int res = ra + rb + azout;
                res = res < 0 ? 0 : (res > 255 ? 255 : res);
                if (st) ob[(size_t)(c0 + r) * HW + pxc[nt]] = res;
            }
        }
        if (s < 3) {
#pragma unroll
            for (int nt = 0; nt < 4; ++nt)
#pragma unroll
                for (int r = 0; r < 4; ++r)
                    xv[nt][r] = xn[nt][r];
        }
    }
}

extern "C" void kernel_launch(void* const* d_in, const int* in_sizes, int n_in,
                              void* d_out, int out_size, void* d_ws, size_t ws_size,
                              hipStream_t stream) {
    const int* x = (const int*)d_in[0];
    const float* w1 = (const float*)d_in[1];
    const float* w2 = (const float*)d_in[2];
    const float* w3 = (const float*)d_in[3];
    const float* bn1_w = (const float*)d_in[4];
    const float* bn1_b = (const float*)d_in[5];
    const float* bn2_w = (const float*)d_in[6];
    const float* bn2_b = (const float*)d_in[7];
    const float* bn3_w = (const float*)d_in[8];
    const float* bn3_b = (const float*)d_in[9];
    const int* conv_zin = (const int*)d_in[10];
    const int* conv_m0 = (const int*)d_in[11];
    const int* conv_shift = (const int*)d_in[12];
    const int* conv_zout = (const int*)d_in[13];
    const int* bn_m0 = (const int*)d_in[14];
    const int* bn_shift = (const int*)d_in[15];
    const int* bn_zout = (const int*)d_in[16];
    const int* add_z = (const int*)d_in[17];
    const int* add_m0 = (const int*)d_in[18];
    const int* add_shift = (const int*)d_in[19];
    const int* add_zout = (const int*)d_in[20];

    v4i* wp = (v4i*)d_ws;
    int* wsum1 = (int*)((char*)d_ws + WP_BYTES);
    signed char* t1 = (signed char*)d_ws + WP_BYTES + WSUM_BYTES;

    const v4i* wp1 = wp;
    const v4i* wp2 = wp + 16 * 64;
    const v4i* wp3 = wp + 52 * 64;

    k_prep<<<dim3(18), dim3(256), 0, stream>>>(w1, w2, w3, wp, wsum1);
    k_conv1<<<dim3(49, 32), dim3(256), 0, stream>>>(x, wp1, wsum1, bn1_w, bn1_b,
        conv_zin, conv_m0, conv_shift, conv_zout, bn_m0, bn_shift, bn_zout, t1);
    k_conv23<<<dim3(56, 32), dim3(256), 0, stream>>>(t1, wp2, wp3,
        bn2_w, bn2_b, bn3_w, bn3_b, x,
        conv_zin, conv_m0, conv_shift, conv_zout, bn_m0, bn_shift, bn_zout,
        add_z, add_m0, add_shift, add_zout, (int*)d_out);
}

// Round 3
// 287.550 us; speedup vs baseline: 1.0675x; 1.0675x over previous
//
#include <hip/hip_runtime.h>

// QuantizedBottleneck via i8 MFMA implicit GEMM. Exact integer math.
//   prep  : pack MFMA A-fragments (w1/w2/w3 -> i8) + wsum1 into d_ws
//   conv1 : 1x1 256->64 + bn1 -> t1 [n][64] i8 (112-px tiles, perm-pack, reg dbuf)
//   conv23: fused 3x3 64->64 pad1 + bn2 -> LDS, then 1x1 64->256 + bn3 +
//           residual add -> out int32. 1-row tiles, grid (56,32).
//           Residual x staged via global_load_lds (VGPR-free, async,
//           double-buffered, counted vmcnt(4), no in-loop barriers).
// Requant uses the exact single-shift identity:
//   ((p+nudge)>>31 + 2^(sh-1))>>sh == (p + nudge + 2^(30+sh)) >> (31+sh)
// conv1 packs raw x bytes ^0x80 (= x-128) and corrects acc by (128-zin)*wsum.
// MFMA 16x16x64_i8: A[m=lane&15][k=(lane>>4)*16+j], B[k][n=lane&15],
// C/D: col=lane&15, row=(lane>>4)*4+reg.

typedef int v4i __attribute__((ext_vector_type(4)));

#define BATCH 32
#define CIN 256
#define CMID 64
#define HW 3136
#define W56 56

#define WP_BYTES ((size_t)68 * 64 * 16)
#define WSUM_BYTES ((size_t)64 * 4)

__device__ __forceinline__ int rq_apply(int acc, int m0, long long cp, long long cn,
                                        int shm1, int zo) {
    long long prod = (long long)acc * m0;
    prod += (prod >= 0) ? cp : cn;
    int hi = (int)((unsigned long long)prod >> 32);
    int v = (hi >> shm1) + zo;
    return v < 0 ? 0 : (v > 255 ? 255 : v);
}

__device__ __forceinline__ int ms_apply(int xin, int m0, long long cp, long long cn,
                                        int shm1) {
    long long prod = (long long)xin * m0;
    prod += (prod >= 0) ? cp : cn;
    return ((int)((unsigned long long)prod >> 32)) >> shm1;
}

// gather byte0 of four ints -> one dword (3 x v_perm_b32)
__device__ __forceinline__ unsigned int pk4x(int a0, int a1, int a2, int a3) {
    unsigned p01 = __builtin_amdgcn_perm((unsigned)a1, (unsigned)a0, 0x00000400u);
    unsigned p23 = __builtin_amdgcn_perm((unsigned)a3, (unsigned)a2, 0x04000000u);
    return __builtin_amdgcn_perm(p23, p01, 0x07060100u);
}

// async global->LDS, 16B per lane: LDS dst (wave-uniform base) + lane*16,
// global src per-lane.
__device__ __forceinline__ void gll16(const int* g, void* l) {
    __builtin_amdgcn_global_load_lds(
        (const __attribute__((address_space(1))) unsigned int*)g,
        (__attribute__((address_space(3))) unsigned int*)l, 16, 0, 0);
}

__device__ __forceinline__ v4i pack16f(const float* src, int stride) {
    v4i r;
#pragma unroll
    for (int d = 0; d < 4; ++d) {
        unsigned int u = 0;
#pragma unroll
        for (int by = 0; by < 4; ++by) {
            int v = (int)src[(d * 4 + by) * stride];
            u |= ((unsigned int)(v & 255)) << (8 * by);
        }
        r[d] = (int)u;
    }
    return r;
}

// -------- prep: fragsets w1 [0,16), w2 [16,52), w3 [52,68); block 17: wsum1 --
__global__ __launch_bounds__(256) void k_prep(
    const float* __restrict__ w1, const float* __restrict__ w2,
    const float* __restrict__ w3, v4i* __restrict__ wp, int* __restrict__ wsum)
{
    if (blockIdx.x < 17) {
        int id = blockIdx.x * 256 + threadIdx.x;
        int fid = id >> 6, lane = id & 63;
        int col = lane & 15, ci0 = (lane >> 4) * 16;
        const float* src;
        int stride;
        if (fid < 16) {
            int wv = fid >> 2, ks = fid & 3;
            src = w1 + (size_t)(wv * 16 + col) * 256 + ks * 64 + ci0;
            stride = 1;
        } else if (fid < 52) {
            int i = fid - 16, wv = i / 9, t = i - wv * 9;
            src = w2 + ((size_t)(wv * 16 + col) * 64 + ci0) * 9 + t;
            stride = 9;
        } else {
            int s = fid - 52;
            src = w3 + (size_t)(s * 16 + col) * 64 + ci0;
            stride = 1;
        }
        wp[fid * 64 + lane] = pack16f(src, stride);
    } else {
        // wsum1[co] = sum_ci w1[co][ci]  (4 threads per channel)
        int ch = threadIdx.x >> 2, t4 = threadIdx.x & 3;
        int s = 0;
        for (int i = 0; i < 64; ++i) s += (int)w1[(size_t)ch * 256 + t4 * 64 + i];
        s += __shfl_xor(s, 1);
        s += __shfl_xor(s, 2);
        if (t4 == 0) wsum[ch] = s;
    }
}

// -------- conv1: 1x1 256->64 + bn1 -> t1. grid (28, 32), 112-px tiles -------
// Staging: thread (cg=tid&7, q=tid>>3, active q<28) loads 8 int4 (4 px, 8 ci)
// per K-step, perm-packs to i8 (^0x80), b64 LDS writes. Register dbuf.
__global__ __launch_bounds__(256, 4) void k_conv1(
    const int* __restrict__ x, const v4i* __restrict__ wp1,
    const int* __restrict__ wsum1,
    const float* __restrict__ bn_w, const float* __restrict__ bn_b,
    const int* __restrict__ conv_zin, const int* __restrict__ conv_m0,
    const int* __restrict__ conv_shift, const int* __restrict__ conv_zout,
    const int* __restrict__ bn_m0, const int* __restrict__ bn_shift,
    const int* __restrict__ bn_zout, signed char* __restrict__ t1)
{
    __shared__ v4i sm[560];                        // 112 px x 80 B
    const int tid = threadIdx.x, lane = tid & 63, wv = tid >> 6;
    const int col = lane & 15, koff = lane >> 4;
    const int b = blockIdx.y;
    const int hw0 = blockIdx.x * 112;
    const int co0 = wv * 16;

    v4i a[4];
#pragma unroll
    for (int ks = 0; ks < 4; ++ks) a[ks] = wp1[(wv * 4 + ks) * 64 + lane];

    const int cg = tid & 7, q = tid >> 3;
    const bool act = q < 28;
    const int* xbase = x + (size_t)b * CIN * HW + hw0 + 4 * q;

    v4i xa[8], xa2[8];
    if (act) {
#pragma unroll
        for (int j = 0; j < 8; ++j)
            xa[j] = *(const v4i*)(xbase + (size_t)(cg * 8 + j) * HW);
    }

    v4i acc[7];
#pragma unroll
    for (int i = 0; i < 7; ++i) acc[i] = (v4i){0, 0, 0, 0};

    unsigned long long* smu = (unsigned long long*)sm;
#pragma unroll
    for (int ks = 0; ks < 4; ++ks) {
        if (ks) __syncthreads();                   // prior MFMA reads done
        if (act) {
#pragma unroll
            for (int p = 0; p < 4; ++p) {
                unsigned lo = pk4x(xa[0][p], xa[1][p], xa[2][p], xa[3][p]) ^ 0x80808080u;
                unsigned hi = pk4x(xa[4][p], xa[5][p], xa[6][p], xa[7][p]) ^ 0x80808080u;
                smu[(q * 4 + p) * 10 + cg] = ((unsigned long long)hi << 32) | lo;
            }
        }
        __syncthreads();
        if (ks < 3 && act) {                       // prefetch next K-step
#pragma unroll
            for (int j = 0; j < 8; ++j)
                xa2[j] = *(const v4i*)(xbase + (size_t)((ks + 1) * 64 + cg * 8 + j) * HW);
        }
#pragma unroll
        for (int nt = 0; nt < 7; ++nt) {
            v4i bf = sm[(nt * 16 + col) * 5 + koff];
            acc[nt] = __builtin_amdgcn_mfma_i32_16x16x64_i8(a[ks], bf, acc[nt], 0, 0, 0);
        }
        if (ks < 3) {
#pragma unroll
            for (int j = 0; j < 8; ++j) xa[j] = xa2[j];
        }
    }

    const int zin = conv_zin[0];
    const int corr0 = 128 - zin;                   // acc was computed vs x-128
    const int cm0 = conv_m0[0], csh = conv_shift[0], czo = conv_zout[0];
    const int bm0 = bn_m0[0], bsh = bn_shift[0], bzo = bn_zout[0];
    const int zin2 = conv_zin[1];
    const long long cbv = 1LL << (30 + csh);
    const long long ccp = cbv + (1LL << 30), ccn = cbv + 1 - (1LL << 30);
    const int cshm1 = csh - 1;
    const long long bbv = 1LL << (30 + bsh);
    const long long bcp = bbv + (1LL << 30), bcn = bbv + 1 - (1LL << 30);
    const int bshm1 = bsh - 1;
    const int rowb = koff * 4;
    int bw[4], bbx[4], ws[4];
#pragma unroll
    for (int r = 0; r < 4; ++r) {
        bw[r] = (int)bn_w[co0 + rowb + r];
        bbx[r] = (int)bn_b[co0 + rowb + r] - czo * bw[r];
        ws[r] = wsum1[co0 + rowb + r];
    }
#pragma unroll
    for (int nt = 0; nt < 7; ++nt) {
        int n = b * HW + hw0 + nt * 16 + col;
        int e[4];
#pragma unroll
        for (int r = 0; r < 4; ++r) {
            int av = acc[nt][r] + corr0 * ws[r];
            int qv = rq_apply(av, cm0, ccp, ccn, cshm1, czo);
            int a2 = qv * bw[r] + bbx[r];
            int q2 = rq_apply(a2, bm0, bcp, bcn, bshm1, bzo);
            e[r] = q2 - zin2;
        }
        *(unsigned*)(t1 + (size_t)n * 64 + co0 + rowb) = pk4x(e[0], e[1], e[2], e[3]);
    }
}

// -------- conv23: fused 3x3+bn2 (-> LDS) then 1x1 64->256 + bn3 + residual --
// grid (56, 32): 1 output row (64 px padded, 56 valid) x batch.
// Phase A: conv2 over 3 halo rows in sm -> t2s LDS (B-frag layout).
// Phase B: 4 fragset steps; residual x arrives via global_load_lds into a
// per-wave double-buffered LDS region, issued one step ahead, counted vmcnt.
__global__ __launch_bounds__(256, 3) void k_conv23(
    const signed char* __restrict__ t1, const v4i* __restrict__ wp2,
    const v4i* __restrict__ wp3,
    const float* __restrict__ bn2_w, const float* __restrict__ bn2_b,
    const float* __restrict__ bn3_w, const float* __restrict__ bn3_b,
    const int* __restrict__ x,
    const int* __restrict__ conv_zin, const int* __restrict__ conv_m0,
    const int* __restrict__ conv_shift, const int* __restrict__ conv_zout,
    const int* __restrict__ bn_m0, const int* __restrict__ bn_shift,
    const int* __restrict__ bn_zout,
    const int* __restrict__ add_z, const int* __restrict__ add_m0,
    const int* __restrict__ add_shift, const int* __restrict__ add_zout,
    int* __restrict__ out)
{
    __shared__ v4i sm[840];                       // 3 rows x 56 px x 80 B
    __shared__ v4i t2s[320];                      // 64 px x 80 B
    __shared__ int xs[2][64][64];                 // [buf][ch][px] 32 KB
    const int tid = threadIdx.x, lane = tid & 63, wv = tid >> 6;
    const int col = lane & 15, koff = lane >> 4;
    const int b = blockIdx.y;
    const int r0 = blockIdx.x;
    const int co0 = wv * 16, rowb = koff * 4;

    v4i a[9];
#pragma unroll
    for (int t = 0; t < 9; ++t) a[t] = wp2[(wv * 9 + t) * 64 + lane];
    v4i a3x[4];
#pragma unroll
    for (int s = 0; s < 4; ++s) a3x[s] = wp3[(wv * 4 + s) * 64 + lane];

    const v4i* t1v = (const v4i*)t1;
#pragma unroll
    for (int k = 0; k < 3; ++k) {
        int idx = tid + k * 256;
        if (idx < 672) {                          // 168 px x 4 parts
            int pixl = idx >> 2, part = idx & 3;
            int lrow = pixl / W56, gw = pixl - lrow * W56;
            int grow = r0 - 1 + lrow;
            v4i v = (v4i){0, 0, 0, 0};
            if ((unsigned)grow < 56u)
                v = t1v[((size_t)b * HW + grow * W56 + gw) * 4 + part];
            sm[pixl * 5 + part] = v;
        }
    }
    __syncthreads();

    // residual x staging: wave wv step t -> channels wv*64+t*16 .. +15.
    // lane l loads 16B of (ch_sub = l>>4, px quad = l&15); LDS slot = lane*16.
    const int* gsrc = x + (size_t)b * CIN * HW + (size_t)r0 * W56;
    int pxl = (lane & 15) * 4;
    if (pxl > 52) pxl = 52;                       // clamp: px>=56 unused
    const int chsub = lane >> 4;
    auto stage = [&](int t) {
        const int chb = wv * 64 + t * 16 + chsub;
#pragma unroll
        for (int j = 0; j < 4; ++j)
            gll16(gsrc + (size_t)(chb + j * 4) * HW + pxl,
                  &xs[t & 1][wv * 16 + j * 4][0]);
    };
    stage(0);
    stage(1);   // both buffers in flight; drained by the pre-phase-B barrier

    v4i acc[4];
#pragma unroll
    for (int i = 0; i < 4; ++i) acc[i] = (v4i){0, 0, 0, 0};

#pragma unroll
    for (int kh = 0; kh < 3; ++kh) {
#pragma unroll
        for (int kw = 0; kw < 3; ++kw) {
            v4i af = a[kh * 3 + kw];
#pragma unroll
            for (int nt = 0; nt < 4; ++nt) {
                int sw = nt * 16 + col + kw - 1;
                bool valid = (unsigned)sw < 56u;
                v4i bf = sm[(kh * W56 + (valid ? sw : 0)) * 5 + koff];
                if (!valid) { bf[0] = 0; bf[1] = 0; bf[2] = 0; bf[3] = 0; }
                acc[nt] = __builtin_amdgcn_mfma_i32_16x16x64_i8(af, bf, acc[nt], 0, 0, 0);
            }
        }
    }

    {   // phase A epilogue: requant + bn2, perm-pack -> t2s (B-frag layout)
        const int cm0 = conv_m0[1], csh = conv_shift[1], czo = conv_zout[1];
        const int bm0 = bn_m0[1], bsh = bn_shift[1], bzo = bn_zout[1];
        const int zin3 = conv_zin[2];
        const long long cbv = 1LL << (30 + csh);
        const long long ccp = cbv + (1LL << 30), ccn = cbv + 1 - (1LL << 30);
        const int cshm1 = csh - 1;
        const long long bbv = 1LL << (30 + bsh);
        const long long bcp = bbv + (1LL << 30), bcn = bbv + 1 - (1LL << 30);
        const int bshm1 = bsh - 1;
        int bw[4], bbx[4];
#pragma unroll
        for (int r = 0; r < 4; ++r) {
            bw[r] = (int)bn2_w[co0 + rowb + r];
            bbx[r] = (int)bn2_b[co0 + rowb + r] - czo * bw[r];
        }
#pragma unroll
        for (int nt = 0; nt < 4; ++nt) {
            int pix = nt * 16 + col;
            int e[4];
#pragma unroll
            for (int r = 0; r < 4; ++r) {
                int qv = rq_apply(acc[nt][r], cm0, ccp, ccn, cshm1, czo);
                int a2 = qv * bw[r] + bbx[r];
                int q2 = rq_apply(a2, bm0, bcp, bcn, bshm1, bzo);
                e[r] = q2 - zin3;
            }
            *(unsigned*)((char*)t2s + (size_t)(pix * 5 + wv) * 16 + koff * 4) =
                pk4x(e[0], e[1], e[2], e[3]);
        }
    }

    // hoist all phase-B params before the loop (keeps the loop vmem-clean)
    const int cm0 = conv_m0[2], csh = conv_shift[2], czo = conv_zout[2];
    const int bm0 = bn_m0[2], bsh = bn_shift[2], bzo = bn_zout[2];
    const long long cb3 = 1LL << (30 + csh);
    const long long ccp = cb3 + (1LL << 30), ccn = cb3 + 1 - (1LL << 30);
    const int cshm1 = csh - 1;
    const long long bb3 = 1LL << (30 + bsh);
    const long long bcp = bb3 + (1LL << 30), bcn = bb3 + 1 - (1LL << 30);
    const int bshm1 = bsh - 1;
    const int az0 = add_z[0], az1 = add_z[1];
    const int am0 = add_m0[0], am1 = add_m0[1];
    const int ash0 = add_shift[0], ash1 = add_shift[1];
    const long long a0b = 1LL << (30 + ash0);
    const long long acp0 = a0b + (1LL << 30), acn0 = a0b + 1 - (1LL << 30);
    const int ashm0 = ash0 - 1;
    const long long a1b = 1LL << (30 + ash1);
    const long long acp1 = a1b + (1LL << 30), acn1 = a1b + 1 - (1LL << 30);
    const int ashm1 = ash1 - 1;
    const int azout = add_zout[0];
    int bw3[4][4], bbx3[4][4];
#pragma unroll
    for (int s = 0; s < 4; ++s)
#pragma unroll
        for (int r = 0; r < 4; ++r) {
            bw3[s][r] = (int)bn3_w[wv * 64 + s * 16 + rowb + r];
            bbx3[s][r] = (int)bn3_b[wv * 64 + s * 16 + rowb + r] - czo * bw3[s][r];
        }

    __syncthreads();   // t2s ready; also drains stage(0)/stage(1) (vmcnt 0)

    int* ob = out + (size_t)b * CIN * HW + (size_t)r0 * W56;

    // phase B main loop: NO barriers (xs is per-wave private).
#pragma unroll
    for (int t = 0; t < 4; ++t) {
        const int c0 = wv * 64 + t * 16;
        v4i acc3[4];
#pragma unroll
        for (int i = 0; i < 4; ++i) acc3[i] = (v4i){0, 0, 0, 0};
#pragma unroll
        for (int nt = 0; nt < 4; ++nt) {
            v4i bf = t2s[(nt * 16 + col) * 5 + koff];
            acc3[nt] = __builtin_amdgcn_mfma_i32_16x16x64_i8(a3x[t], bf, acc3[nt], 0, 0, 0);
        }
        // xs[t&1] ready when everything but stage(t+1)'s 4 glls has retired.
        asm volatile("s_waitcnt vmcnt(4)" ::: "memory");
        __builtin_amdgcn_sched_barrier(0);
#pragma unroll
        for (int nt = 0; nt < 4; ++nt) {
            int px = nt * 16 + col;
            bool st = px < 56;
#pragma unroll
            for (int r = 0; r < 4; ++r) {
                int xr = xs[t & 1][co0 + rowb + r][px];
                int qv = rq_apply(acc3[nt][r], cm0, ccp, ccn, cshm1, czo);
                int a2 = qv * bw3[t][r] + bbx3[t][r];
                int q2 = rq_apply(a2, bm0, bcp, bcn, bshm1, bzo);
                int ra = ms_apply(xr - az0, am0, acp0, acn0, ashm0);
                int rb = ms_apply(q2 - az1, am1, acp1, acn1, ashm1);
                int res = ra + rb + azout;
                res = res < 0 ? 0 : (res > 255 ? 255 : res);
                if (st) ob[(size_t)(c0 + rowb + r) * HW + px] = res;
            }
        }
        if (t < 2) {
            // xs reads retired before re-staging this buffer
            asm volatile("s_waitcnt lgkmcnt(0)" ::: "memory");
            __builtin_amdgcn_sched_barrier(0);
            stage(t + 2);
        }
    }
}

extern "C" void kernel_launch(void* const* d_in, const int* in_sizes, int n_in,
                              void* d_out, int out_size, void* d_ws, size_t ws_size,
                              hipStream_t stream) {
    const int* x = (const int*)d_in[0];
    const float* w1 = (const float*)d_in[1];
    const float* w2 = (const float*)d_in[2];
    const float* w3 = (const float*)d_in[3];
    const float* bn1_w = (const float*)d_in[4];
    const float* bn1_b = (const float*)d_in[5];
    const float* bn2_w = (const float*)d_in[6];
    const float* bn2_b = (const float*)d_in[7];
    const float* bn3_w = (const float*)d_in[8];
    const float* bn3_b = (const float*)d_in[9];
    const int* conv_zin = (const int*)d_in[10];
    const int* conv_m0 = (const int*)d_in[11];
    const int* conv_shift = (const int*)d_in[12];
    const int* conv_zout = (const int*)d_in[13];
    const int* bn_m0 = (const int*)d_in[14];
    const int* bn_shift = (const int*)d_in[15];
    const int* bn_zout = (const int*)d_in[16];
    const int* add_z = (const int*)d_in[17];
    const int* add_m0 = (const int*)d_in[18];
    const int* add_shift = (const int*)d_in[19];
    const int* add_zout = (const int*)d_in[20];

    v4i* wp = (v4i*)d_ws;
    int* wsum1 = (int*)((char*)d_ws + WP_BYTES);
    signed char* t1 = (signed char*)d_ws + WP_BYTES + WSUM_BYTES;

    const v4i* wp1 = wp;
    const v4i* wp2 = wp + 16 * 64;
    const v4i* wp3 = wp + 52 * 64;

    k_prep<<<dim3(18), dim3(256), 0, stream>>>(w1, w2, w3, wp, wsum1);
    k_conv1<<<dim3(28, 32), dim3(256), 0, stream>>>(x, wp1, wsum1, bn1_w, bn1_b,
        conv_zin, conv_m0, conv_shift, conv_zout, bn_m0, bn_shift, bn_zout, t1);
    k_conv23<<<dim3(56, 32), dim3(256), 0, stream>>>(t1, wp2, wp3,
        bn2_w, bn2_b, bn3_w, bn3_b, x,
        conv_zin, conv_m0, conv_shift, conv_zout, bn_m0, bn_shift, bn_zout,
        add_z, add_m0, add_shift, add_zout, (int*)d_out);
}